// Round 1
// baseline (839.722 us; speedup 1.0000x reference)
//
#include <hip/hip_runtime.h>
#include <math.h>

#define BATCH 16
#define HWPIX 36864      // 192*192
#define CCH 128
#define NCACHE 5
#define SCALE 0.125f
#define THRESH 0.7f
#define EPSV 1e-8f

typedef _Float16 f16;
typedef __attribute__((ext_vector_type(8))) _Float16 f16x8;
typedef __attribute__((ext_vector_type(4))) float f32x4;

// ---------------- kpre1: M1, M2, M12 (fp32) + canonical-f16 M12, Q, W2 ----------------
// canonical B-operand layout for mfma_f32_16x16x32_f16:
//   idx = ((k>>3)*128 + n)*8 + (k&7)   (lane reads 8 contiguous f16 = b128)
__global__ __launch_bounds__(256) void kpre1(
    const float* __restrict__ A1, const float* __restrict__ B1,
    const float* __restrict__ A2, const float* __restrict__ B2,
    const float* __restrict__ W1, const float* __restrict__ W2,
    const float* __restrict__ cache_w,
    float* __restrict__ M1f, float* __restrict__ M12f,
    f16* __restrict__ M12h, f16* __restrict__ Qh, f16* __restrict__ W2h) {
  __shared__ float M1s[128 * 16];
  __shared__ float M2s[16 * 128];
  int t = threadIdx.x;
  for (int idx = t; idx < 2048; idx += 256) {
    int i = idx >> 4, r = idx & 15;
    float s = 0.f;
    for (int k = 0; k < 8; ++k) s += A1[i * 8 + k] * B1[k * 16 + r];
    s *= SCALE;
    M1s[idx] = s;
    M1f[idx] = s;
  }
  for (int idx = t; idx < 2048; idx += 256) {
    int r = idx >> 7, j = idx & 127;
    float s = 0.f;
    for (int k = 0; k < 8; ++k) s += A2[r * 8 + k] * B2[k * 128 + j];
    M2s[idx] = s * SCALE;
  }
  __syncthreads();
  for (int idx = t; idx < 16384; idx += 256) {
    int i = idx >> 7, j = idx & 127;
    float s = 0.f;
    for (int r = 0; r < 16; ++r) s += M1s[i * 16 + r] * M2s[r * 128 + j];
    M12f[idx] = s;
    M12h[(((i >> 3) * 128 + j) << 3) + (i & 7)] = (f16)s;
  }
  float cw = 1.f / (1.f + __expf(-cache_w[0]));
  float qs = 1.f - cw;
  for (int idx = t; idx < 16384; idx += 256) {
    int k = idx >> 7, n = idx & 127;
    int ci = (((k >> 3) * 128 + n) << 3) + (k & 7);
    Qh[ci] = (f16)(qs * W1[k * 128 + n]);
    W2h[ci] = (f16)W2[k * 128 + n];
  }
}

// ---------------- kpre2: P = cw*(M12@W1a) + M1@W1b, canonical f16 ----------------
__global__ __launch_bounds__(256) void kpre2(
    const float* __restrict__ W1, const float* __restrict__ M1f,
    const float* __restrict__ M12f, const float* __restrict__ cache_w,
    f16* __restrict__ Ph) {
  int t = threadIdx.x;
  int k = blockIdx.x * 8 + (t >> 5);
  int n0 = (t & 31) * 4;
  float cw = 1.f / (1.f + __expf(-cache_w[0]));
  float sa[4] = {0, 0, 0, 0}, sb[4] = {0, 0, 0, 0};
  for (int tt = 0; tt < 128; ++tt) {
    float m = M12f[k * 128 + tt];
    const float* wr = &W1[tt * 128 + n0];
    sa[0] += m * wr[0]; sa[1] += m * wr[1]; sa[2] += m * wr[2]; sa[3] += m * wr[3];
  }
  for (int r = 0; r < 16; ++r) {
    float m = M1f[k * 16 + r];
    const float* wr = &W1[(128 + r) * 128 + n0];
    sb[0] += m * wr[0]; sb[1] += m * wr[1]; sb[2] += m * wr[2]; sb[3] += m * wr[3];
  }
  for (int u = 0; u < 4; ++u) {
    int n = n0 + u;
    Ph[(((k >> 3) * 128 + n) << 3) + (k & 7)] = (f16)(cw * sa[u] + sb[u]);
  }
}

// ---------------- k2: x_lora = x@M12 (MFMA), write out, accumulate num/xn2/cn2 ----------------
__global__ __launch_bounds__(256) void k2(
    const float* __restrict__ x, const float* __restrict__ cache,
    const f16* __restrict__ M12h, float* __restrict__ out,
    float* __restrict__ num, float* __restrict__ xn2, float* __restrict__ cn2) {
  __shared__ f16 Bs[16 * 128 * 8];   // 32 KB: M12 canonical
  __shared__ f16 As[16 * 64 * 8];    // 16 KB: x tile canonical (M=64)
  __shared__ f16 XLb[64 * 132];      // x_lora tile, padded stride
  __shared__ float nacc[2][5][128];
  __shared__ float x2acc[2][128];
  int t = threadIdx.x;
  int chunk = blockIdx.x;   // 0..575
  int grp = blockIdx.y;     // 0..1
  long pb = (long)chunk * 64;
  {
    const uint4* src = (const uint4*)M12h;
    uint4* dst = (uint4*)Bs;
    for (int i = t; i < 2048; i += 256) dst[i] = src[i];
  }
  int lane = t & 63, w = t >> 6, l15 = lane & 15, q = lane >> 4;
  for (int g = 0; g < 8; ++g) {
    int b = grp * 8 + g;
    const float* xb = x + ((long)b * HWPIX + pb) * CCH;
    __syncthreads();
    // stage x tile -> As (fp32 -> f16, canonical A layout)
    for (int i = 0; i < 8; ++i) {
      int f = i * 256 + t;                 // float4 index, 0..2047
      int p = f >> 5, c4 = (f & 31) << 2;  // pixel row, channel base
      float4 v = ((const float4*)xb)[f];
      f16* d = &As[(((c4 >> 3) * 64 + p) << 3) + (c4 & 7)];
      d[0] = (f16)v.x; d[1] = (f16)v.y; d[2] = (f16)v.z; d[3] = (f16)v.w;
    }
    __syncthreads();
    // GEMM: 64 pixels x 128 ch, K=128
    f32x4 acc[8];
    for (int ni = 0; ni < 8; ++ni) acc[ni] = 0;
    for (int kk = 0; kk < 4; ++kk) {
      f16x8 a = *(const f16x8*)&As[(((kk * 4 + q) * 64 + (w * 16 + l15)) << 3)];
      for (int ni = 0; ni < 8; ++ni) {
        f16x8 bb = *(const f16x8*)&Bs[(((kk * 4 + q) * 128 + ni * 16 + l15)) << 3];
        acc[ni] = __builtin_amdgcn_mfma_f32_16x16x32_f16(a, bb, acc[ni], 0, 0, 0);
      }
    }
    // epilogue: out (fp32) + XLb (f16)
    float* ob = out + ((long)b * HWPIX + pb) * CCH;
    for (int ni = 0; ni < 8; ++ni) {
      int c = ni * 16 + l15;
      for (int r = 0; r < 4; ++r) {
        int p = w * 16 + q * 4 + r;
        float v = acc[ni][r];
        ob[(long)p * CCH + c] = v;
        XLb[p * 132 + c] = (f16)v;
      }
    }
    __syncthreads();
    // num / xn2 (/cn2 once) partials: thread = (channel, pixel-half)
    {
      int c = t & 127, half = t >> 7;
      bool docn = (grp == 0) && (g == 0);
      float s2 = 0, sn0 = 0, sn1 = 0, sn2 = 0, sn3 = 0, sn4 = 0;
      float sc0 = 0, sc1 = 0, sc2 = 0, sc3 = 0, sc4 = 0;
      const float* cb = cache + pb * CCH + c;
      for (int pp = 0; pp < 32; ++pp) {
        int p = half * 32 + pp;
        float xl = (float)XLb[p * 132 + c];
        s2 += xl * xl;
        float cv0 = cb[((long)0 * HWPIX + p) * CCH];
        float cv1 = cb[((long)1 * HWPIX + p) * CCH];
        float cv2 = cb[((long)2 * HWPIX + p) * CCH];
        float cv3 = cb[((long)3 * HWPIX + p) * CCH];
        float cv4 = cb[((long)4 * HWPIX + p) * CCH];
        sn0 += xl * cv0; sn1 += xl * cv1; sn2 += xl * cv2;
        sn3 += xl * cv3; sn4 += xl * cv4;
        if (docn) {
          sc0 += cv0 * cv0; sc1 += cv1 * cv1; sc2 += cv2 * cv2;
          sc3 += cv3 * cv3; sc4 += cv4 * cv4;
        }
      }
      nacc[half][0][c] = sn0; nacc[half][1][c] = sn1; nacc[half][2][c] = sn2;
      nacc[half][3][c] = sn3; nacc[half][4][c] = sn4;
      x2acc[half][c] = s2;
      if (docn) {
        atomicAdd(&cn2[0 * 128 + c], sc0);
        atomicAdd(&cn2[1 * 128 + c], sc1);
        atomicAdd(&cn2[2 * 128 + c], sc2);
        atomicAdd(&cn2[3 * 128 + c], sc3);
        atomicAdd(&cn2[4 * 128 + c], sc4);
      }
    }
    __syncthreads();
    for (int idx = t; idx < 640; idx += 256) {
      int n = idx >> 7, cc = idx & 127;
      atomicAdd(&num[((long)b * 5 + n) * 128 + cc],
                nacc[0][n][cc] + nacc[1][n][cc]);
    }
    if (t < 128) atomicAdd(&xn2[b * 128 + t], x2acc[0][t] + x2acc[1][t]);
  }
}

// ---------------- k3: sims -> best_idx, mask ----------------
__global__ __launch_bounds__(128) void k3(
    const float* __restrict__ num, const float* __restrict__ xn2v,
    const float* __restrict__ cn2v, int* __restrict__ stats) {
  __shared__ float sims[16][5];
  int t = threadIdx.x;
  if (t < 80) {
    int b = t / 5, n = t % 5;
    float s = 0.f;
    for (int c = 0; c < 128; ++c) {
      float xn = sqrtf(xn2v[b * 128 + c]);
      float cn = sqrtf(cn2v[n * 128 + c]);
      s += num[(b * 5 + n) * 128 + c] / (fmaxf(xn, EPSV) * fmaxf(cn, EPSV));
    }
    sims[b][n] = s * (1.f / 128.f);
  }
  __syncthreads();
  if (t < 16) {
    float bv = -1e30f;
    int bi = 0;
    for (int n = 0; n < 5; ++n) {
      float v = sims[t][n];
      if (v > bv) { bv = v; bi = n; }   // strict > keeps first max
    }
    stats[t] = bi;
    stats[16 + t] = (bv > THRESH) ? 1 : 0;
  }
}

// ---------------- k4: fused = silu(x@P + best@Q + b1)@W2 + b2 for masked batches ----------------
__global__ __launch_bounds__(256) void k4(
    const float* __restrict__ x, const float* __restrict__ cache,
    const f16* __restrict__ Ph, const f16* __restrict__ Qh,
    const f16* __restrict__ W2h, const float* __restrict__ b1,
    const float* __restrict__ b2, const int* __restrict__ stats,
    float* __restrict__ out) {
  int b = blockIdx.y;
  if (!stats[16 + b]) return;
  __shared__ f16 Bs[16 * 128 * 8];
  __shared__ f16 As[16 * 64 * 8];
  __shared__ float b1s[128], b2s[128];
  int t = threadIdx.x;
  if (t < 128) { b1s[t] = b1[t]; b2s[t] = b2[t]; }
  int bi = stats[b];
  long pb = (long)blockIdx.x * 64;
  const float* xb = x + ((long)b * HWPIX + pb) * CCH;
  const float* cbest = cache + ((long)bi * HWPIX + pb) * CCH;
  int lane = t & 63, w = t >> 6, l15 = lane & 15, q = lane >> 4;

  auto stageA = [&](const float* __restrict__ src) {
    for (int i = 0; i < 8; ++i) {
      int f = i * 256 + t;
      int p = f >> 5, c4 = (f & 31) << 2;
      float4 v = ((const float4*)src)[f];
      f16* d = &As[(((c4 >> 3) * 64 + p) << 3) + (c4 & 7)];
      d[0] = (f16)v.x; d[1] = (f16)v.y; d[2] = (f16)v.z; d[3] = (f16)v.w;
    }
  };
  auto loadB = [&](const f16* __restrict__ src) {
    const uint4* s = (const uint4*)src;
    uint4* d = (uint4*)Bs;
    for (int i = t; i < 2048; i += 256) d[i] = s[i];
  };
  auto gemm = [&](f32x4* ac) {
    for (int kk = 0; kk < 4; ++kk) {
      f16x8 a = *(const f16x8*)&As[(((kk * 4 + q) * 64 + (w * 16 + l15)) << 3)];
      for (int ni = 0; ni < 8; ++ni) {
        f16x8 bb = *(const f16x8*)&Bs[(((kk * 4 + q) * 128 + ni * 16 + l15)) << 3];
        ac[ni] = __builtin_amdgcn_mfma_f32_16x16x32_f16(a, bb, ac[ni], 0, 0, 0);
      }
    }
  };

  f32x4 acc[8];
  for (int ni = 0; ni < 8; ++ni) acc[ni] = 0;
  loadB(Ph);
  stageA(xb);
  __syncthreads();
  gemm(acc);                 // x@P
  __syncthreads();
  loadB(Qh);
  stageA(cbest);
  __syncthreads();
  gemm(acc);                 // += best@Q
  // silu(acc + b1) -> As (each wave writes only its own 16 rows; wave-local dep)
  for (int ni = 0; ni < 8; ++ni) {
    int c = ni * 16 + l15;
    for (int r = 0; r < 4; ++r) {
      int p = w * 16 + q * 4 + r;
      float hv = acc[ni][r] + b1s[c];
      float sv = hv / (1.f + __expf(-hv));
      As[(((c >> 3) * 64 + p) << 3) + (c & 7)] = (f16)sv;
    }
  }
  __syncthreads();
  loadB(W2h);
  __syncthreads();
  f32x4 acc2[8];
  for (int ni = 0; ni < 8; ++ni) acc2[ni] = 0;
  gemm(acc2);                // silu@W2
  float* ob = out + ((long)b * HWPIX + pb) * CCH;
  for (int ni = 0; ni < 8; ++ni) {
    int c = ni * 16 + l15;
    for (int r = 0; r < 4; ++r) {
      int p = w * 16 + q * 4 + r;
      ob[(long)p * CCH + c] = acc2[ni][r] + b2s[c];
    }
  }
}

// ---------------- launch ----------------
extern "C" void kernel_launch(void* const* d_in, const int* in_sizes, int n_in,
                              void* d_out, int out_size, void* d_ws, size_t ws_size,
                              hipStream_t stream) {
  const float* x  = (const float*)d_in[0];
  const float* A1 = (const float*)d_in[1];
  const float* B1 = (const float*)d_in[2];
  const float* A2 = (const float*)d_in[3];
  const float* B2 = (const float*)d_in[4];
  const float* W1 = (const float*)d_in[5];
  const float* b1 = (const float*)d_in[6];
  const float* W2 = (const float*)d_in[7];
  const float* b2 = (const float*)d_in[8];
  const float* cache_w = (const float*)d_in[9];
  const float* cache   = (const float*)d_in[10];
  float* out = (float*)d_out;
  char* wsb = (char*)d_ws;
  float* num  = (float*)(wsb + 0);       // 16*5*128 f
  float* xn2  = (float*)(wsb + 40960);   // 16*128 f
  float* cn2  = (float*)(wsb + 49152);   // 5*128 f
  int*   stats= (int*)  (wsb + 51712);   // best_idx[16], mask[16]
  float* M1f  = (float*)(wsb + 51840);   // 128*16 f
  float* M12f = (float*)(wsb + 60032);   // 128*128 f
  f16*   M12h = (f16*)  (wsb + 125568);  // canonical f16, 32KB each
  f16*   Ph   = (f16*)  (wsb + 158336);
  f16*   Qh   = (f16*)  (wsb + 191104);
  f16*   W2h  = (f16*)  (wsb + 223872);

  hipMemsetAsync(wsb, 0, 51712, stream);  // zero num/xn2/cn2
  kpre1<<<1, 256, 0, stream>>>(A1, B1, A2, B2, W1, W2, cache_w, M1f, M12f, M12h, Qh, W2h);
  kpre2<<<16, 256, 0, stream>>>(W1, M1f, M12f, cache_w, Ph);
  k2<<<dim3(576, 2), 256, 0, stream>>>(x, cache, M12h, out, num, xn2, cn2);
  k3<<<1, 128, 0, stream>>>(num, xn2, cn2, stats);
  k4<<<dim3(576, 16), 256, 0, stream>>>(x, cache, Ph, Qh, W2h, b1, b2, stats, out);
}